// Round 5
// baseline (499.064 us; speedup 1.0000x reference)
//
#include <hip/hip_runtime.h>

// MoveModule: out[idx[k]] = (leaky_relu(nf[idx[k]] @ W1 + b1) @ W2 + b2), zeros elsewhere.
// N=500000, D=128, H=128, M=4, K=250000, fp32 (no fp32 MFMA on CDNA4).
//
// R4 post-mortem: 165us, VALUBusy=53%, conflicts=0, HBM 5.5%. Measured 26k cyc/64-row tile
// == 2048 ds_read_b128 x 12cyc (m134) -> LDS ISSUE-BOUND. Fix: cut reads/FMA 2x via 8x8
// per-thread blocking: 256 thr, 128x128 tile, single x/h buffer + reg-prefetch of next gather.
// Model: ~28.6k cyc per 128-row tile -> ~91us. Occupancy drops to 4 waves/CU (LDS pipe is
// CU-level; acceptable).

#define D_DIM 128
#define H_DIM 128
#define M_DIM 4
#define ROWS 128
#define XSTR 132          // pad: rg-stride-132 reads land on distinct bank quads (4*rg%32)
#define NT 256

__global__ void zero_out_kernel(float4* __restrict__ out, int n4) {
    int i = blockIdx.x * blockDim.x + threadIdx.x;
    int stride = gridDim.x * blockDim.x;
    float4 z = make_float4(0.f, 0.f, 0.f, 0.f);
    for (; i < n4; i += stride) out[i] = z;
}

__global__ __launch_bounds__(NT, 1)
void mlp_v3_kernel(const float* __restrict__ nf,
                   const int* __restrict__ idx,
                   const float* __restrict__ W1,
                   const float* __restrict__ b1,
                   const float* __restrict__ W2,
                   const float* __restrict__ b2,
                   float* __restrict__ out,
                   int K, int ntiles) {
    __shared__ float w1s[D_DIM * H_DIM];   // 64 KB, [d][j]
    __shared__ float xh[ROWS * XSTR];      // 67.6 KB: x tile, then h tile
    __shared__ float w2s[H_DIM * M_DIM];   // [j][m]
    __shared__ float b1s[H_DIM];
    __shared__ float b2s[M_DIM];

    const int tid = threadIdx.x;

    // Stage weights once per block.
    for (int i = tid; i < D_DIM * H_DIM / 4; i += NT)
        ((float4*)w1s)[i] = ((const float4*)W1)[i];
    if (tid < H_DIM * M_DIM / 4) ((float4*)w2s)[tid] = ((const float4*)W2)[tid];
    if (tid < H_DIM) b1s[tid] = b1[tid];
    if (tid < M_DIM) b2s[tid] = b2[tid];

    // Compute mapping: rg in 0..15 (rows rg+16i, i=0..7), cg in 0..15 (cols 8cg..8cg+7).
    // rg = (lane&3)+4*wave, cg = lane>>2: quarter-wave has 4 rg (banks 4rg: distinct quads)
    // and 4 cg (banks 8cg%32: distinct quads) -> all layer-1 reads conflict-free.
    const int lane = tid & 63, wvi = tid >> 6;
    const int rg = (lane & 3) + 4 * wvi;
    const int cg = (lane >> 2) & 15;
    const int j0 = cg * 8;

    // Staging mapping: thread covers rows qrow+8i (i=0..15), float4-slot f4.
    const int qrow = tid >> 5;    // 0..7
    const int f4 = tid & 31;      // 0..31

    const int stride_t = gridDim.x;
    float4 px[16];

    // Guarded gather of tile tt's x into px registers.
    auto load_px = [&](int tt) {
        #pragma unroll
        for (int i = 0; i < 16; ++i) {
            int row = qrow + 8 * i;
            int g = tt * ROWS + row;
            int gi = (tt < ntiles && g < K) ? idx[g] : -1;
            px[i] = make_float4(0.f, 0.f, 0.f, 0.f);
            if (gi >= 0)
                px[i] = *(const float4*)(nf + (long long)gi * D_DIM + f4 * 4);
        }
    };

    // ---- Prologue: stage tile blockIdx.x into LDS.
    int t = blockIdx.x;
    load_px(t);
    #pragma unroll
    for (int i = 0; i < 16; ++i)
        *(float4*)(&xh[(qrow + 8 * i) * XSTR + f4 * 4]) = px[i];
    __syncthreads();   // weights + first x tile visible

    const int r2 = tid >> 1;            // layer-2 row
    const int mb = (tid & 1) * 2;       // layer-2 output pair {mb, mb+1}

    for (; t < ntiles; t += stride_t) {
        // --- Phase A: issue next tile's gather (hides under layer 1), preload this
        //     tile's scatter index, then layer-1 8x8 register-blocked GEMM.
        int g2 = t * ROWS + r2;
        int gi_cur = (g2 < K) ? idx[g2] : -1;
        load_px(t + stride_t);

        float acc[8][8];
        #pragma unroll
        for (int i = 0; i < 8; ++i)
            #pragma unroll
            for (int c = 0; c < 8; ++c) acc[i][c] = b1s[j0 + c];

        for (int d = 0; d < D_DIM; d += 4) {
            float4 wa[4], wb[4];
            #pragma unroll
            for (int dd = 0; dd < 4; ++dd) {
                wa[dd] = *(const float4*)(w1s + (d + dd) * H_DIM + j0);
                wb[dd] = *(const float4*)(w1s + (d + dd) * H_DIM + j0 + 4);
            }
            #pragma unroll
            for (int i = 0; i < 8; ++i) {
                float4 xv = *(const float4*)(xh + (rg + 16 * i) * XSTR + d);
                float xa[4] = {xv.x, xv.y, xv.z, xv.w};
                #pragma unroll
                for (int dd = 0; dd < 4; ++dd) {
                    acc[i][0] += xa[dd] * wa[dd].x;
                    acc[i][1] += xa[dd] * wa[dd].y;
                    acc[i][2] += xa[dd] * wa[dd].z;
                    acc[i][3] += xa[dd] * wa[dd].w;
                    acc[i][4] += xa[dd] * wb[dd].x;
                    acc[i][5] += xa[dd] * wb[dd].y;
                    acc[i][6] += xa[dd] * wb[dd].z;
                    acc[i][7] += xa[dd] * wb[dd].w;
                }
            }
        }
        __syncthreads();   // barrier 1: all x reads done, buffer free for h

        // --- Phase B: leaky_relu, write h tile (2-way max per quarter-wave = free).
        #pragma unroll
        for (int i = 0; i < 8; ++i) {
            float4 h0, h1;
            h0.x = acc[i][0] > 0.f ? acc[i][0] : acc[i][0] * 0.01f;
            h0.y = acc[i][1] > 0.f ? acc[i][1] : acc[i][1] * 0.01f;
            h0.z = acc[i][2] > 0.f ? acc[i][2] : acc[i][2] * 0.01f;
            h0.w = acc[i][3] > 0.f ? acc[i][3] : acc[i][3] * 0.01f;
            h1.x = acc[i][4] > 0.f ? acc[i][4] : acc[i][4] * 0.01f;
            h1.y = acc[i][5] > 0.f ? acc[i][5] : acc[i][5] * 0.01f;
            h1.z = acc[i][6] > 0.f ? acc[i][6] : acc[i][6] * 0.01f;
            h1.w = acc[i][7] > 0.f ? acc[i][7] : acc[i][7] * 0.01f;
            float* hp = xh + (rg + 16 * i) * XSTR + j0;
            *(float4*)(hp) = h0;
            *(float4*)(hp + 4) = h1;
        }
        __syncthreads();   // barrier 2: h visible

        // --- Phase C: layer 2 — each thread: one row, two m-outputs.
        {
            float y0 = b2s[mb], y1 = b2s[mb + 1];
            const float* hb = xh + r2 * XSTR;
            #pragma unroll 8
            for (int j = 0; j < H_DIM; j += 4) {
                float4 hv = *(const float4*)(hb + j);
                y0 += hv.x * w2s[(j + 0) * M_DIM + mb]
                    + hv.y * w2s[(j + 1) * M_DIM + mb]
                    + hv.z * w2s[(j + 2) * M_DIM + mb]
                    + hv.w * w2s[(j + 3) * M_DIM + mb];
                y1 += hv.x * w2s[(j + 0) * M_DIM + mb + 1]
                    + hv.y * w2s[(j + 1) * M_DIM + mb + 1]
                    + hv.z * w2s[(j + 2) * M_DIM + mb + 1]
                    + hv.w * w2s[(j + 3) * M_DIM + mb + 1];
            }
            if (gi_cur >= 0)
                *(float2*)(out + (long long)gi_cur * M_DIM + mb) = make_float2(y0, y1);
        }
        __syncthreads();   // barrier 3: h reads done, buffer free for next x

        // --- Phase D: write prefetched next-tile x (loads landed during layer 1).
        #pragma unroll
        for (int i = 0; i < 16; ++i)
            *(float4*)(&xh[(qrow + 8 * i) * XSTR + f4 * 4]) = px[i];
        __syncthreads();   // barrier 4: next x visible
    }
}

extern "C" void kernel_launch(void* const* d_in, const int* in_sizes, int n_in,
                              void* d_out, int out_size, void* d_ws, size_t ws_size,
                              hipStream_t stream) {
    const float* nf  = (const float*)d_in[0];
    const int*   idx = (const int*)d_in[1];
    const float* W1  = (const float*)d_in[2];
    const float* b1  = (const float*)d_in[3];
    const float* W2  = (const float*)d_in[4];
    const float* b2  = (const float*)d_in[5];
    float* out = (float*)d_out;
    const int K = in_sizes[1];

    // d_out is poisoned 0xAA before every launch -> zero it.
    int n4 = out_size / 4;
    hipLaunchKernelGGL(zero_out_kernel, dim3(1024), dim3(256), 0, stream,
                       (float4*)out, n4);

    int ntiles = (K + ROWS - 1) / ROWS;
    int grid = ntiles < 256 ? ntiles : 256;   // 1 blk/CU (135.7 KB LDS), grid-stride tiles
    hipLaunchKernelGGL(mlp_v3_kernel, dim3(grid), dim3(NT), 0, stream,
                       nf, idx, W1, b1, W2, b2, out, K, ntiles);
}